// Round 6
// baseline (228.482 us; speedup 1.0000x reference)
//
#include <hip/hip_runtime.h>
#include <hip/hip_bf16.h>
#include <stdint.h>

typedef __attribute__((ext_vector_type(8))) short bfrag;
typedef __attribute__((ext_vector_type(4))) short bfrag4;
typedef __attribute__((ext_vector_type(4))) float f32x4;
typedef __attribute__((ext_vector_type(2))) float f32x2;
typedef __attribute__((ext_vector_type(2))) unsigned int u32x2;
typedef __attribute__((ext_vector_type(4))) unsigned int u32x4;

__device__ inline short f2bf(float f) {
  union { float f; uint32_t u; } v; v.f = f;
  uint32_t u = v.u;
  uint32_t r = (u + 0x7fffu + ((u >> 16) & 1u)) >> 16;
  return (short)r;
}
__device__ inline float bf2f(short s) {
  return __builtin_bit_cast(float, (uint32_t)((uint32_t)(uint16_t)s << 16));
}

#if __has_builtin(__builtin_amdgcn_cvt_pk_bf16_f32)
typedef __attribute__((ext_vector_type(2))) __bf16 bf16x2_t;
__device__ inline uint32_t pack_bf16(float a, float b) {
  bf16x2_t r = __builtin_amdgcn_cvt_pk_bf16_f32(a, b);
  return __builtin_bit_cast(uint32_t, r);
}
#else
__device__ inline uint32_t pack_bf16(float a, float b) {
  uint32_t ua = __builtin_bit_cast(uint32_t, a) + 0x8000u;
  uint32_t ub = __builtin_bit_cast(uint32_t, b) + 0x8000u;
  return __builtin_amdgcn_perm(ub, ua, 0x07060302);
}
#endif

// Drain-free workgroup barrier: only my own LDS ops must be complete.
__device__ inline void lds_barrier() {
  asm volatile("s_waitcnt lgkmcnt(0)" ::: "memory");
  __builtin_amdgcn_s_barrier();
  asm volatile("" ::: "memory");
}

// ---------------- prep: ada (blocks 0-15) + weight transposes (16-79) ------
__global__ __launch_bounds__(256) void prep_kernel(
    const float* __restrict__ emb_table, const int* __restrict__ t,
    const float* __restrict__ ada_w, const float* __restrict__ ada_b,
    float* __restrict__ scsh,
    const float* __restrict__ qkv_w, short* __restrict__ qkv_wt,
    const float* __restrict__ proj_w, short* __restrict__ proj_wt) {
  __shared__ float smem[64 * 65];
  const int blk = blockIdx.x;
  const int tid = threadIdx.x;
  if (blk < 16) {
    float* se = smem;
    float* part = smem + 256;
    int b = blk >> 3, ox = blk & 7;
    int tt = t[b];
    float e = emb_table[tt * 256 + tid];
    se[tid] = e / (1.f + __expf(-e));
    __syncthreads();
    int ol = tid & 63, kc = tid >> 6;
    int o = ox * 64 + ol;
    float acc = 0.f;
#pragma unroll 8
    for (int k = kc * 64; k < (kc + 1) * 64; ++k) acc += se[k] * ada_w[k * 512 + o];
    part[tid] = acc;
    __syncthreads();
    if (tid < 64) {
      int oo = ox * 64 + tid;
      scsh[b * 512 + oo] =
          part[tid] + part[64 + tid] + part[128 + tid] + part[192 + tid] + ada_b[oo];
    }
  } else {
    const float* W; short* Wt; int N, lb;
    if (blk < 64) { W = qkv_w; Wt = qkv_wt; N = 768; lb = blk - 16; }
    else          { W = proj_w; Wt = proj_wt; N = 256; lb = blk - 64; }
    float (*tile)[65] = (float(*)[65])smem;
    int k0 = (lb & 3) * 64, n0 = (lb >> 2) * 64;
    int r = tid >> 2, c0 = (tid & 3) * 16;
    const float* src = W + (long)(k0 + r) * N + n0 + c0;
#pragma unroll
    for (int j = 0; j < 16; j += 4) {
      float4 v = *(const float4*)(src + j);
      tile[r][c0 + j] = v.x; tile[r][c0 + j + 1] = v.y;
      tile[r][c0 + j + 2] = v.z; tile[r][c0 + j + 3] = v.w;
    }
    __syncthreads();
    int nl = tid >> 2, kc = (tid & 3) * 16;
    short outv[16];
#pragma unroll
    for (int j = 0; j < 16; ++j) outv[j] = f2bf(tile[kc + j][nl]);
    short* dst = Wt + (long)(n0 + nl) * 256 + k0 + kc;
    *(bfrag*)dst = *(bfrag*)&outv[0];
    *(bfrag*)(dst + 8) = *(bfrag*)&outv[8];
  }
}

// ---------------- LayerNorm + (1+sc)*xn + sh -> bf16, wave-per-row ---------
__global__ __launch_bounds__(256) void ln_kernel(const float* __restrict__ x,
                                                 const float* __restrict__ scsh,
                                                 short* __restrict__ xb) {
  int row = blockIdx.x * 4 + (threadIdx.x >> 6);   // 2048 blocks x 4 rows
  int b = row >> 12;
  int lane = threadIdx.x & 63;
  float4 v = *(const float4*)(x + (long)row * 256 + lane * 4);
  float s = v.x + v.y + v.z + v.w;
  float sq = v.x * v.x + v.y * v.y + v.z * v.z + v.w * v.w;
#pragma unroll
  for (int off = 32; off > 0; off >>= 1) {
    s += __shfl_xor(s, off);
    sq += __shfl_xor(sq, off);
  }
  float mu = s * (1.f / 256.f);
  float var = sq * (1.f / 256.f) - mu * mu;
  float rstd = rsqrtf(var + 1e-5f);
  const float* scp = scsh + b * 512 + lane * 4;
  float4 sc = *(const float4*)scp;
  float4 sh = *(const float4*)(scp + 256);
  float y0 = (v.x - mu) * rstd * (1.f + sc.x) + sh.x;
  float y1 = (v.y - mu) * rstd * (1.f + sc.y) + sh.y;
  float y2 = (v.z - mu) * rstd * (1.f + sc.z) + sh.z;
  float y3 = (v.w - mu) * rstd * (1.f + sc.w) + sh.w;
  u32x2 o; o.x = pack_bf16(y0, y1); o.y = pack_bf16(y2, y3);
  *(u32x2*)&xb[(long)row * 256 + lane * 4] = o;
}

// ---------------- QKV GEMM, 128x64 tile: qkv = xb * qkv_wt^T + bias --------
// cols 0..511 -> qk bf16 (cols<256 scaled by qscale); 512..767 -> vT (transposed).
__global__ __launch_bounds__(256) void gemm_qkv(const short* __restrict__ A,
                                                const short* __restrict__ Bt,
                                                const float* __restrict__ bias,
                                                float qscale,
                                                short* __restrict__ qk,
                                                short* __restrict__ vT) {
  __shared__ short As[128 * 40];
  __shared__ short Bs[64 * 40];
  const int mt = blockIdx.x, nt = blockIdx.y;
  const int tid = threadIdx.x;
  const int w = tid >> 6, lane = tid & 63, l16 = lane & 15, quad = lane >> 4;
  const int ar = tid >> 1, ak = (tid & 1) * 16;
  const int br = tid >> 2, bk = (tid & 3) * 8;
  f32x4 acc[2][4] = {};
  const short* Arow = A + (long)(mt * 128 + ar) * 256 + ak;
  const short* Brow = Bt + (long)(nt * 64 + br) * 256 + bk;
  bfrag a8a = *(const bfrag*)Arow;
  bfrag a8b = *(const bfrag*)(Arow + 8);
  bfrag b8  = *(const bfrag*)Brow;
  for (int kk = 0; kk < 8; ++kk) {
    __syncthreads();
    *(bfrag*)&As[ar * 40 + ak] = a8a;
    *(bfrag*)&As[ar * 40 + ak + 8] = a8b;
    *(bfrag*)&Bs[br * 40 + bk] = b8;
    __syncthreads();
    int kn = (kk < 7) ? (kk + 1) : 7;
    a8a = *(const bfrag*)(Arow + kn * 32);
    a8b = *(const bfrag*)(Arow + kn * 32 + 8);
    b8  = *(const bfrag*)(Brow + kn * 32);
    bfrag a0 = *(const bfrag*)&As[(w * 32 + l16) * 40 + quad * 8];
    bfrag a1 = *(const bfrag*)&As[(w * 32 + 16 + l16) * 40 + quad * 8];
#pragma unroll
    for (int c = 0; c < 4; ++c) {
      bfrag bf = *(const bfrag*)&Bs[(c * 16 + l16) * 40 + quad * 8];
      acc[0][c] = __builtin_amdgcn_mfma_f32_16x16x32_bf16(a0, bf, acc[0][c], 0, 0, 0);
      acc[1][c] = __builtin_amdgcn_mfma_f32_16x16x32_bf16(a1, bf, acc[1][c], 0, 0, 0);
    }
  }
  const int rowb = mt * 128 + w * 32 + quad * 4;
  if (nt < 8) {  // Q,K columns -> qk pitch 512
#pragma unroll
    for (int rg = 0; rg < 2; ++rg) {
      int row0 = rowb + rg * 16;
#pragma unroll
      for (int c = 0; c < 4; ++c) {
        int col = nt * 64 + c * 16 + l16;
        float bv = bias[col];
        float mult = (col < 256) ? qscale : 1.0f;
#pragma unroll
        for (int r = 0; r < 4; ++r)
          qk[(long)(row0 + r) * 512 + col] = f2bf((acc[rg][c][r] + bv) * mult);
      }
    }
  } else {  // V columns -> vT[bh][d][key]
    const int bb = mt >> 5;
#pragma unroll
    for (int rg = 0; rg < 2; ++rg) {
      int keyl = (rowb + rg * 16) & 4095;
#pragma unroll
      for (int c = 0; c < 4; ++c) {
        int col = nt * 64 + c * 16 + l16;
        float bv = bias[col];
        int d = col - 512;
        u32x2 dd;
        dd.x = pack_bf16(acc[rg][c][0] + bv, acc[rg][c][1] + bv);
        dd.y = pack_bf16(acc[rg][c][2] + bv, acc[rg][c][3] + bv);
        *(u32x2*)&vT[((long)(bb * 8 + (d >> 5)) * 32 + (d & 31)) * 4096 + keyl] = dd;
      }
    }
  }
}

// ---------------- flash attention (S^T, O^T PV, prefetch depth 2) ----------
// Grid: 2048 blocks, XCD-aware mapping, 128 q rows/block, keys [ks*1024,+1024).
// T4: two register prefetch pairs alternate; the load for tile i+2 issues
// right after barrier i, so the vmcnt wait before each ds_write has ~2 full
// compute phases of slack (counted vmcnt, never a full drain).
__global__ __launch_bounds__(256) void attn_kernel(const short* __restrict__ qk,
                                                   const short* __restrict__ vT,
                                                   short* __restrict__ OpB,
                                                   float* __restrict__ lpart) {
  const int bid = blockIdx.x;
  const int c = bid & 7, j = bid >> 3;          // bijective: 2048 = 8 * 256
  const int bh = c * 2 + (j >> 7);
  const int qt = j & 31;
  const int ks = (j >> 5) & 3;
  const int b = bh >> 3, hh = bh & 7;
  const int tid = threadIdx.x;
  const int w = tid >> 6, lane = tid & 63, l16 = lane & 15, quad = lane >> 4;
  const int sig0 = ((l16 >> 2) * 8) + (l16 & 3);   // key-slot permutation

  __shared__ short Ks[2][64 * 36];
  __shared__ short Vt[2][32 * 68];

  const long rowbase = (long)b * 4096;
  const int qrow0 = qt * 128 + w * 32 + l16;       // q index for Q-frag / lsum
  bfrag qf[2];
#pragma unroll
  for (int g = 0; g < 2; ++g)
    qf[g] = *(const bfrag*)&qk[(rowbase + qrow0 + g * 16) * 512 + hh * 32 + quad * 8];

  f32x4 olo[2] = {}, ohi[2] = {};   // O^T accum: rows q=4*quad+r, col d=l16(+16)
  f32x2 lsum[2] = {};

  const int si = tid >> 2, sk = (tid & 3) * 8;
  const int vrow = tid >> 3, vcol = (tid & 7) * 8;
  const short* ksrc = qk + rowbase * 512 + 256 + hh * 32 + (long)si * 512 + sk;
  const short* vsrc = vT + ((long)bh * 32 + vrow) * 4096 + vcol;

  const int kt0 = ks * 16;
  // prefetch tiles 0 and 1 (depth 2)
  bfrag kA = *(const bfrag*)(ksrc + (long)kt0 * 64 * 512);
  bfrag vA = *(const bfrag*)(vsrc + kt0 * 64);
  bfrag kB = *(const bfrag*)(ksrc + (long)(kt0 + 1) * 64 * 512);
  bfrag vB = *(const bfrag*)(vsrc + (kt0 + 1) * 64);

  auto compute = [&](const short* KsB, const short* VtB) {
#pragma unroll
    for (int p = 0; p < 2; ++p) {              // 32-key pair-tiles
      const int kb = p * 32;
      bfrag kf0 = *(const bfrag*)&KsB[(kb + sig0) * 36 + quad * 8];
      bfrag kf1 = *(const bfrag*)&KsB[(kb + sig0 + 4) * 36 + quad * 8];
      f32x4 z = {0, 0, 0, 0};
      f32x4 s0[2], s1[2];
      __builtin_amdgcn_s_setprio(1);
      s0[0] = __builtin_amdgcn_mfma_f32_16x16x32_bf16(kf0, qf[0], z, 0, 0, 0);
      s0[1] = __builtin_amdgcn_mfma_f32_16x16x32_bf16(kf0, qf[1], z, 0, 0, 0);
      s1[0] = __builtin_amdgcn_mfma_f32_16x16x32_bf16(kf1, qf[0], z, 0, 0, 0);
      s1[1] = __builtin_amdgcn_mfma_f32_16x16x32_bf16(kf1, qf[1], z, 0, 0, 0);
      __builtin_amdgcn_s_setprio(0);
      bfrag pb[2];
#pragma unroll
      for (int g = 0; g < 2; ++g) {
        float e0 = __builtin_amdgcn_exp2f(s0[g][0]);
        float e1 = __builtin_amdgcn_exp2f(s0[g][1]);
        float e2 = __builtin_amdgcn_exp2f(s0[g][2]);
        float e3 = __builtin_amdgcn_exp2f(s0[g][3]);
        float f0 = __builtin_amdgcn_exp2f(s1[g][0]);
        float f1 = __builtin_amdgcn_exp2f(s1[g][1]);
        float f2 = __builtin_amdgcn_exp2f(s1[g][2]);
        float f3 = __builtin_amdgcn_exp2f(s1[g][3]);
        f32x2 pa = {e0, e1}, pbv = {e2, e3}, pc = {f0, f1}, pd = {f2, f3};
        lsum[g] += pa; lsum[g] += pbv; lsum[g] += pc; lsum[g] += pd;
        u32x4 pk;
        pk.x = pack_bf16(e0, e1); pk.y = pack_bf16(e2, e3);
        pk.z = pack_bf16(f0, f1); pk.w = pack_bf16(f2, f3);
        pb[g] = __builtin_bit_cast(bfrag, pk);
      }
      bfrag vlo = *(const bfrag*)&VtB[l16 * 68 + kb + quad * 8];
      bfrag vhi = *(const bfrag*)&VtB[(16 + l16) * 68 + kb + quad * 8];
      __builtin_amdgcn_s_setprio(1);
#pragma unroll
      for (int g = 0; g < 2; ++g) {
        olo[g] = __builtin_amdgcn_mfma_f32_16x16x32_bf16(pb[g], vlo, olo[g], 0, 0, 0);
        ohi[g] = __builtin_amdgcn_mfma_f32_16x16x32_bf16(pb[g], vhi, ohi[g], 0, 0, 0);
      }
      __builtin_amdgcn_s_setprio(0);
    }
  };

  for (int ii = 0; ii < 8; ++ii) {
    // even iteration (tile 2*ii) -> buf 0, regs A
    *(bfrag*)&Ks[0][si * 36 + sk] = kA;
    *(bfrag*)&Vt[0][vrow * 68 + vcol] = vA;
    lds_barrier();
    {
      int nn = (ii < 7) ? (2 * ii + 2) : 15;
      kA = *(const bfrag*)(ksrc + (long)(kt0 + nn) * 64 * 512);
      vA = *(const bfrag*)(vsrc + (kt0 + nn) * 64);
    }
    compute(Ks[0], Vt[0]);
    // odd iteration (tile 2*ii+1) -> buf 1, regs B
    *(bfrag*)&Ks[1][si * 36 + sk] = kB;
    *(bfrag*)&Vt[1][vrow * 68 + vcol] = vB;
    lds_barrier();
    {
      int nn = (ii < 7) ? (2 * ii + 3) : 15;
      kB = *(const bfrag*)(ksrc + (long)(kt0 + nn) * 64 * 512);
      vB = *(const bfrag*)(vsrc + (kt0 + nn) * 64);
    }
    compute(Ks[1], Vt[1]);
  }

  // epilogue: O^T layout -> OpB[q][d] u16 stores (once per block)
  uint16_t* Ob = (uint16_t*)OpB;
  const long obase = ((long)ks * 16 + bh) * 4096;
  const int qgb = qt * 128 + w * 32;
#pragma unroll
  for (int g = 0; g < 2; ++g) {
    float ls = lsum[g].x + lsum[g].y;
    ls += __shfl_xor(ls, 16); ls += __shfl_xor(ls, 32);
    if (quad == 0)
      lpart[obase + qrow0 + g * 16] = ls;
#pragma unroll
    for (int r = 0; r < 4; ++r) {
      int q = qgb + g * 16 + quad * 4 + r;
      uint32_t pk = pack_bf16(olo[g][r], ohi[g][r]);
      Ob[(obase + q) * 32 + l16] = (uint16_t)pk;
      Ob[(obase + q) * 32 + l16 + 16] = (uint16_t)(pk >> 16);
    }
  }
}

// ---------------- proj GEMM with fused key-split reduce --------------------
// A[row][d] = (sum_ks OpB) / (sum_ks lpart), computed during A-staging.
// Head hh == kk (K-step index): A cols kk*32..+31 come from OpB head kk.
// C = A[8192,256] * proj_wt^T + proj_b -> fp32 out. Grid (64,4), 128x64 tile.
__global__ __launch_bounds__(256) void proj_kernel(const short* __restrict__ OpB,
                                                   const float* __restrict__ lpart,
                                                   const short* __restrict__ Bt,
                                                   const float* __restrict__ bias,
                                                   float* __restrict__ out) {
  __shared__ short As[128 * 40];
  __shared__ short Bs[64 * 40];
  const int mt = blockIdx.x, nt = blockIdx.y;
  const int tid = threadIdx.x;
  const int w = tid >> 6, lane = tid & 63, l16 = lane & 15, quad = lane >> 4;
  const int ar = tid >> 1, ak = (tid & 1) * 16;   // A: 128 rows x 32 cols/iter
  const int br = tid >> 2, bk = (tid & 3) * 8;
  f32x4 acc[2][4] = {};

  const int row = mt * 128 + ar;
  const int q = row & 4095, bq = row >> 12;
  const short* Brow = Bt + (long)(nt * 64 + br) * 256 + bk;

  // prefetch kk=0 (head hh = kk; OpB row index = (ks*16 + bq*8 + kk)*4096 + q)
  long lb0 = (long)(bq * 8) * 4096 + q;
  bfrag pa[4][2];            // [ks][half]: 16 shorts per ks = d ak..ak+15
  f32x4 pl;
#pragma unroll
  for (int ks = 0; ks < 4; ++ks) {
    long base = (lb0 + (long)ks * 16 * 4096) * 32 + ak;
    pa[ks][0] = *(const bfrag*)&OpB[base];
    pa[ks][1] = *(const bfrag*)&OpB[base + 8];
    pl[ks] = lpart[lb0 + (long)ks * 16 * 4096];
  }
  bfrag b8 = *(const bfrag*)Brow;

  for (int kk = 0; kk < 8; ++kk) {
    // combine partials -> bf16 A fragment
    float linv = 1.f / (pl[0] + pl[1] + pl[2] + pl[3]);
    short av[16];
#pragma unroll
    for (int h = 0; h < 2; ++h) {
#pragma unroll
      for (int j = 0; j < 8; j += 2) {
        float v0 = (bf2f(pa[0][h][j]) + bf2f(pa[1][h][j]) +
                    bf2f(pa[2][h][j]) + bf2f(pa[3][h][j])) * linv;
        float v1 = (bf2f(pa[0][h][j+1]) + bf2f(pa[1][h][j+1]) +
                    bf2f(pa[2][h][j+1]) + bf2f(pa[3][h][j+1])) * linv;
        *(uint32_t*)&av[h * 8 + j] = pack_bf16(v0, v1);
      }
    }
    __syncthreads();
    *(bfrag*)&As[ar * 40 + ak] = *(bfrag*)&av[0];
    *(bfrag*)&As[ar * 40 + ak + 8] = *(bfrag*)&av[8];
    *(bfrag*)&Bs[br * 40 + bk] = b8;
    __syncthreads();
    // prefetch next kk
    int kn = (kk < 7) ? (kk + 1) : 7;
    long lbn = (long)(bq * 8 + kn) * 4096 + q;
#pragma unroll
    for (int ks = 0; ks < 4; ++ks) {
      long base = (lbn + (long)ks * 16 * 4096) * 32 + ak;
      pa[ks][0] = *(const bfrag*)&OpB[base];
      pa[ks][1] = *(const bfrag*)&OpB[base + 8];
      pl[ks] = lpart[lbn + (long)ks * 16 * 4096];
    }
    b8 = *(const bfrag*)(Brow + kn * 32);

    bfrag a0 = *(const bfrag*)&As[(w * 32 + l16) * 40 + quad * 8];
    bfrag a1 = *(const bfrag*)&As[(w * 32 + 16 + l16) * 40 + quad * 8];
#pragma unroll
    for (int c = 0; c < 4; ++c) {
      bfrag bf = *(const bfrag*)&Bs[(c * 16 + l16) * 40 + quad * 8];
      acc[0][c] = __builtin_amdgcn_mfma_f32_16x16x32_bf16(a0, bf, acc[0][c], 0, 0, 0);
      acc[1][c] = __builtin_amdgcn_mfma_f32_16x16x32_bf16(a1, bf, acc[1][c], 0, 0, 0);
    }
  }
  const int rowb = mt * 128 + w * 32 + quad * 4;
#pragma unroll
  for (int rg = 0; rg < 2; ++rg) {
    int row0 = rowb + rg * 16;
#pragma unroll
    for (int c = 0; c < 4; ++c) {
      int col = nt * 64 + c * 16 + l16;
      float bv = bias[col];
#pragma unroll
      for (int r = 0; r < 4; ++r)
        out[(long)(row0 + r) * 256 + col] = acc[rg][c][r] + bv;
    }
  }
}

extern "C" void kernel_launch(void* const* d_in, const int* in_sizes, int n_in,
                              void* d_out, int out_size, void* d_ws, size_t ws_size,
                              hipStream_t stream) {
  const float* x      = (const float*)d_in[0];
  // d_in[1] = cond (unused by reference)
  const int*   t      = (const int*)d_in[2];
  const float* emb    = (const float*)d_in[3];
  const float* ada_w  = (const float*)d_in[4];
  const float* ada_b  = (const float*)d_in[5];
  const float* qkv_w  = (const float*)d_in[6];
  const float* qkv_b  = (const float*)d_in[7];
  const float* proj_w = (const float*)d_in[8];
  const float* proj_b = (const float*)d_in[9];

  char* ws = (char*)d_ws;
  float* scsh     = (float*)(ws);                  //   4 KB  [2][512]
  short* qkv_wt   = (short*)(ws + 4096);           // 384 KB  [768][256]
  short* proj_wt  = (short*)(ws + 397312);         // 128 KB  [256][256]
  short* xb       = (short*)(ws + 528384);         //   4 MB  [8192][256]
  short* qk_out   = (short*)(ws + 4722688);        //   8 MB  [8192][512]
  short* vT       = (short*)(ws + 13111296);       //   4 MB  [16][32][4096]
  short* OpB      = (short*)(ws + 21499904);       //  16 MB  [4][16][4096][32] bf16
  float* lpart    = (float*)(ws + 38277120);       //   1 MB  [4][16][4096]

  const float QS = 0.17677669529663687f * 1.4426950408889634f;  // scale*log2e

  prep_kernel<<<80, 256, 0, stream>>>(emb, t, ada_w, ada_b, scsh,
                                      qkv_w, qkv_wt, proj_w, proj_wt);
  ln_kernel<<<2048, 256, 0, stream>>>(x, scsh, xb);
  gemm_qkv<<<dim3(64, 12), 256, 0, stream>>>(xb, qkv_wt, qkv_b, QS, qk_out, vT);
  attn_kernel<<<2048, 256, 0, stream>>>(qk_out, vT, OpB, lpart);
  proj_kernel<<<dim3(64, 4), 256, 0, stream>>>(OpB, lpart, proj_wt, proj_b,
                                               (float*)d_out);
}

// Round 8
// 170.519 us; speedup vs baseline: 1.3399x; 1.3399x over previous
//
#include <hip/hip_runtime.h>
#include <hip/hip_bf16.h>
#include <stdint.h>

typedef __attribute__((ext_vector_type(8))) short bfrag;
typedef __attribute__((ext_vector_type(4))) short bfrag4;
typedef __attribute__((ext_vector_type(4))) float f32x4;
typedef __attribute__((ext_vector_type(2))) float f32x2;
typedef __attribute__((ext_vector_type(2))) unsigned int u32x2;
typedef __attribute__((ext_vector_type(4))) unsigned int u32x4;

__device__ inline short f2bf(float f) {
  union { float f; uint32_t u; } v; v.f = f;
  uint32_t u = v.u;
  uint32_t r = (u + 0x7fffu + ((u >> 16) & 1u)) >> 16;
  return (short)r;
}
__device__ inline float bf2f(short s) {
  return __builtin_bit_cast(float, (uint32_t)((uint32_t)(uint16_t)s << 16));
}

#if __has_builtin(__builtin_amdgcn_cvt_pk_bf16_f32)
typedef __attribute__((ext_vector_type(2))) __bf16 bf16x2_t;
__device__ inline uint32_t pack_bf16(float a, float b) {
  bf16x2_t r = __builtin_amdgcn_cvt_pk_bf16_f32(a, b);
  return __builtin_bit_cast(uint32_t, r);
}
#else
__device__ inline uint32_t pack_bf16(float a, float b) {
  uint32_t ua = __builtin_bit_cast(uint32_t, a) + 0x8000u;
  uint32_t ub = __builtin_bit_cast(uint32_t, b) + 0x8000u;
  return __builtin_amdgcn_perm(ub, ua, 0x07060302);
}
#endif

// Drain-free workgroup barrier: only my own LDS ops must be complete.
__device__ inline void lds_barrier() {
  asm volatile("s_waitcnt lgkmcnt(0)" ::: "memory");
  __builtin_amdgcn_s_barrier();
  asm volatile("" ::: "memory");
}

// ---------------- prep: ada (0-15) + transposes (16-79) + LN-norm (80+) ----
// LN blocks write xn = (x-mu)*rstd as FP32 (no rounding before the affine;
// the affine + single bf16 rounding happens in gemm_qkv staging -> same
// arithmetic/rounding points as the unfused R5 baseline).
__global__ __launch_bounds__(256) void prep_kernel(
    const float* __restrict__ emb_table, const int* __restrict__ t,
    const float* __restrict__ ada_w, const float* __restrict__ ada_b,
    float* __restrict__ scsh,
    const float* __restrict__ qkv_w, short* __restrict__ qkv_wt,
    const float* __restrict__ proj_w, short* __restrict__ proj_wt,
    const float* __restrict__ x, float* __restrict__ xn) {
  __shared__ float smem[64 * 65];
  const int blk = blockIdx.x;
  const int tid = threadIdx.x;
  if (blk >= 80) {  // LayerNorm normalize: 2048 blocks x 4 rows
    int row = (blk - 80) * 4 + (tid >> 6);
    int lane = tid & 63;
    float4 v = *(const float4*)(x + (long)row * 256 + lane * 4);
    float s = v.x + v.y + v.z + v.w;
    float sq = v.x * v.x + v.y * v.y + v.z * v.z + v.w * v.w;
#pragma unroll
    for (int off = 32; off > 0; off >>= 1) {
      s += __shfl_xor(s, off);
      sq += __shfl_xor(sq, off);
    }
    float mu = s * (1.f / 256.f);
    float var = sq * (1.f / 256.f) - mu * mu;
    float rstd = rsqrtf(var + 1e-5f);
    float4 o;
    o.x = (v.x - mu) * rstd; o.y = (v.y - mu) * rstd;
    o.z = (v.z - mu) * rstd; o.w = (v.w - mu) * rstd;
    *(float4*)&xn[(long)row * 256 + lane * 4] = o;
    return;
  }
  if (blk < 16) {
    float* se = smem;
    float* part = smem + 256;
    int b = blk >> 3, ox = blk & 7;
    int tt = t[b];
    float e = emb_table[tt * 256 + tid];
    se[tid] = e / (1.f + __expf(-e));
    __syncthreads();
    int ol = tid & 63, kc = tid >> 6;
    int o = ox * 64 + ol;
    float acc = 0.f;
#pragma unroll 8
    for (int k = kc * 64; k < (kc + 1) * 64; ++k) acc += se[k] * ada_w[k * 512 + o];
    part[tid] = acc;
    __syncthreads();
    if (tid < 64) {
      int oo = ox * 64 + tid;
      scsh[b * 512 + oo] =
          part[tid] + part[64 + tid] + part[128 + tid] + part[192 + tid] + ada_b[oo];
    }
  } else {
    const float* W; short* Wt; int N, lb;
    if (blk < 64) { W = qkv_w; Wt = qkv_wt; N = 768; lb = blk - 16; }
    else          { W = proj_w; Wt = proj_wt; N = 256; lb = blk - 64; }
    float (*tile)[65] = (float(*)[65])smem;
    int k0 = (lb & 3) * 64, n0 = (lb >> 2) * 64;
    int r = tid >> 2, c0 = (tid & 3) * 16;
    const float* src = W + (long)(k0 + r) * N + n0 + c0;
#pragma unroll
    for (int j = 0; j < 16; j += 4) {
      float4 v = *(const float4*)(src + j);
      tile[r][c0 + j] = v.x; tile[r][c0 + j + 1] = v.y;
      tile[r][c0 + j + 2] = v.z; tile[r][c0 + j + 3] = v.w;
    }
    __syncthreads();
    int nl = tid >> 2, kc = (tid & 3) * 16;
    short outv[16];
#pragma unroll
    for (int j = 0; j < 16; ++j) outv[j] = f2bf(tile[kc + j][nl]);
    short* dst = Wt + (long)(n0 + nl) * 256 + k0 + kc;
    *(bfrag*)dst = *(bfrag*)&outv[0];
    *(bfrag*)(dst + 8) = *(bfrag*)&outv[8];
  }
}

// ---------------- QKV GEMM with fused LN affine (fp32 xn input) ------------
// A[row][col] = xn[row][col]*(1+sc[b][col]) + sh[b][col], fp32 math, single
// bf16 rounding at LDS staging. 1-D grid 768, XCD-swizzled (XCD c owns mt
// {c*8..c*8+7}, all nt -> 1 MB x-slice per XCD stays L2-resident).
__global__ __launch_bounds__(256) void gemm_qkv(const float* __restrict__ A,
                                                const float* __restrict__ scsh,
                                                const short* __restrict__ Bt,
                                                const float* __restrict__ bias,
                                                float qscale,
                                                short* __restrict__ qk,
                                                short* __restrict__ vT) {
  __shared__ short As[128 * 40];
  __shared__ short Bs[64 * 40];
  const int bid = blockIdx.x;
  const int cx = bid & 7, jj = bid >> 3;        // 768 = 8 * 96
  const int mt = cx * 8 + (jj & 7);
  const int nt = jj >> 3;                       // 0..11
  const int tid = threadIdx.x;
  const int w = tid >> 6, lane = tid & 63, l16 = lane & 15, quad = lane >> 4;
  const int ar = tid >> 1, ak = (tid & 1) * 16;
  const int br = tid >> 2, bk = (tid & 3) * 8;
  f32x4 acc[2][4] = {};
  const int arow_g = mt * 128 + ar;
  const float* scb = scsh + (arow_g >> 12) * 512;
  const float* Arow = A + (long)arow_g * 256 + ak;
  const short* Brow = Bt + (long)(nt * 64 + br) * 256 + bk;
  float4 xa0 = *(const float4*)(Arow);
  float4 xa1 = *(const float4*)(Arow + 4);
  float4 xa2 = *(const float4*)(Arow + 8);
  float4 xa3 = *(const float4*)(Arow + 12);
  bfrag b8  = *(const bfrag*)Brow;
  for (int kk = 0; kk < 8; ++kk) {
    int cb = kk * 32 + ak;
    float xv[16], scv[16], shv[16];
    *(float4*)&xv[0] = xa0; *(float4*)&xv[4] = xa1;
    *(float4*)&xv[8] = xa2; *(float4*)&xv[12] = xa3;
    *(float4*)&scv[0]  = *(const float4*)(scb + cb);
    *(float4*)&scv[4]  = *(const float4*)(scb + cb + 4);
    *(float4*)&scv[8]  = *(const float4*)(scb + cb + 8);
    *(float4*)&scv[12] = *(const float4*)(scb + cb + 12);
    *(float4*)&shv[0]  = *(const float4*)(scb + 256 + cb);
    *(float4*)&shv[4]  = *(const float4*)(scb + 256 + cb + 4);
    *(float4*)&shv[8]  = *(const float4*)(scb + 256 + cb + 8);
    *(float4*)&shv[12] = *(const float4*)(scb + 256 + cb + 12);
    short av[16];
#pragma unroll
    for (int j = 0; j < 16; j += 2) {
      float y0 = xv[j]     * (1.f + scv[j])     + shv[j];
      float y1 = xv[j + 1] * (1.f + scv[j + 1]) + shv[j + 1];
      *(uint32_t*)&av[j] = pack_bf16(y0, y1);
    }
    __syncthreads();
    *(bfrag*)&As[ar * 40 + ak] = *(bfrag*)&av[0];
    *(bfrag*)&As[ar * 40 + ak + 8] = *(bfrag*)&av[8];
    *(bfrag*)&Bs[br * 40 + bk] = b8;
    __syncthreads();
    int kn = (kk < 7) ? (kk + 1) : 7;
    xa0 = *(const float4*)(Arow + kn * 32);
    xa1 = *(const float4*)(Arow + kn * 32 + 4);
    xa2 = *(const float4*)(Arow + kn * 32 + 8);
    xa3 = *(const float4*)(Arow + kn * 32 + 12);
    b8  = *(const bfrag*)(Brow + kn * 32);
    bfrag a0 = *(const bfrag*)&As[(w * 32 + l16) * 40 + quad * 8];
    bfrag a1 = *(const bfrag*)&As[(w * 32 + 16 + l16) * 40 + quad * 8];
#pragma unroll
    for (int c = 0; c < 4; ++c) {
      bfrag bf = *(const bfrag*)&Bs[(c * 16 + l16) * 40 + quad * 8];
      acc[0][c] = __builtin_amdgcn_mfma_f32_16x16x32_bf16(a0, bf, acc[0][c], 0, 0, 0);
      acc[1][c] = __builtin_amdgcn_mfma_f32_16x16x32_bf16(a1, bf, acc[1][c], 0, 0, 0);
    }
  }
  const int rowb = mt * 128 + w * 32 + quad * 4;
  if (nt < 8) {  // Q,K columns -> qk pitch 512
#pragma unroll
    for (int rg = 0; rg < 2; ++rg) {
      int row0 = rowb + rg * 16;
#pragma unroll
      for (int c = 0; c < 4; ++c) {
        int col = nt * 64 + c * 16 + l16;
        float bv = bias[col];
        float mult = (col < 256) ? qscale : 1.0f;
#pragma unroll
        for (int r = 0; r < 4; ++r)
          qk[(long)(row0 + r) * 512 + col] = f2bf((acc[rg][c][r] + bv) * mult);
      }
    }
  } else {  // V columns -> vT[bh][d][key]
    const int bb = mt >> 5;
#pragma unroll
    for (int rg = 0; rg < 2; ++rg) {
      int keyl = (rowb + rg * 16) & 4095;
#pragma unroll
      for (int c = 0; c < 4; ++c) {
        int col = nt * 64 + c * 16 + l16;
        float bv = bias[col];
        int d = col - 512;
        u32x2 dd;
        dd.x = pack_bf16(acc[rg][c][0] + bv, acc[rg][c][1] + bv);
        dd.y = pack_bf16(acc[rg][c][2] + bv, acc[rg][c][3] + bv);
        *(u32x2*)&vT[((long)(bb * 8 + (d >> 5)) * 32 + (d & 31)) * 4096 + keyl] = dd;
      }
    }
  }
}

// ---------------- flash attention (R5: S^T, O^T PV via 16x16x32) -----------
__global__ __launch_bounds__(256) void attn_kernel(const short* __restrict__ qk,
                                                   const short* __restrict__ vT,
                                                   short* __restrict__ OpB,
                                                   float* __restrict__ lpart) {
  const int bid = blockIdx.x;
  const int c = bid & 7, j = bid >> 3;          // bijective: 2048 = 8 * 256
  const int bh = c * 2 + (j >> 7);
  const int qt = j & 31;
  const int ks = (j >> 5) & 3;
  const int b = bh >> 3, hh = bh & 7;
  const int tid = threadIdx.x;
  const int w = tid >> 6, lane = tid & 63, l16 = lane & 15, quad = lane >> 4;
  const int sig0 = ((l16 >> 2) * 8) + (l16 & 3);   // key-slot permutation

  __shared__ short Ks[2][64 * 36];
  __shared__ short Vt[2][32 * 68];

  const long rowbase = (long)b * 4096;
  const int qrow0 = qt * 128 + w * 32 + l16;
  bfrag qf[2];
#pragma unroll
  for (int g = 0; g < 2; ++g)
    qf[g] = *(const bfrag*)&qk[(rowbase + qrow0 + g * 16) * 512 + hh * 32 + quad * 8];

  f32x4 olo[2] = {}, ohi[2] = {};
  f32x2 lsum[2] = {};

  const int si = tid >> 2, sk = (tid & 3) * 8;
  const int vrow = tid >> 3, vcol = (tid & 7) * 8;
  const short* ksrc = qk + rowbase * 512 + 256 + hh * 32 + (long)si * 512 + sk;
  const short* vsrc = vT + ((long)bh * 32 + vrow) * 4096 + vcol;

  const int kt0 = ks * 16;
  bfrag k8 = *(const bfrag*)(ksrc + (long)kt0 * 64 * 512);
  bfrag v8 = *(const bfrag*)(vsrc + kt0 * 64);

  int buf = 0;
  for (int i = 0; i < 16; ++i) {
    *(bfrag*)&Ks[buf][si * 36 + sk] = k8;
    *(bfrag*)&Vt[buf][vrow * 68 + vcol] = v8;
    lds_barrier();
    int nn = (i < 15) ? (i + 1) : 15;
    k8 = *(const bfrag*)(ksrc + (long)(kt0 + nn) * 64 * 512);
    v8 = *(const bfrag*)(vsrc + (kt0 + nn) * 64);

#pragma unroll
    for (int p = 0; p < 2; ++p) {
      const int kb = p * 32;
      bfrag kf0 = *(const bfrag*)&Ks[buf][(kb + sig0) * 36 + quad * 8];
      bfrag kf1 = *(const bfrag*)&Ks[buf][(kb + sig0 + 4) * 36 + quad * 8];
      f32x4 z = {0, 0, 0, 0};
      f32x4 s0[2], s1[2];
      __builtin_amdgcn_s_setprio(1);
      s0[0] = __builtin_amdgcn_mfma_f32_16x16x32_bf16(kf0, qf[0], z, 0, 0, 0);
      s0[1] = __builtin_amdgcn_mfma_f32_16x16x32_bf16(kf0, qf[1], z, 0, 0, 0);
      s1[0] = __builtin_amdgcn_mfma_f32_16x16x32_bf16(kf1, qf[0], z, 0, 0, 0);
      s1[1] = __builtin_amdgcn_mfma_f32_16x16x32_bf16(kf1, qf[1], z, 0, 0, 0);
      __builtin_amdgcn_s_setprio(0);
      bfrag pb[2];
#pragma unroll
      for (int g = 0; g < 2; ++g) {
        float e0 = __builtin_amdgcn_exp2f(s0[g][0]);
        float e1 = __builtin_amdgcn_exp2f(s0[g][1]);
        float e2 = __builtin_amdgcn_exp2f(s0[g][2]);
        float e3 = __builtin_amdgcn_exp2f(s0[g][3]);
        float f0 = __builtin_amdgcn_exp2f(s1[g][0]);
        float f1 = __builtin_amdgcn_exp2f(s1[g][1]);
        float f2 = __builtin_amdgcn_exp2f(s1[g][2]);
        float f3 = __builtin_amdgcn_exp2f(s1[g][3]);
        f32x2 pa = {e0, e1}, pbv = {e2, e3}, pc = {f0, f1}, pd = {f2, f3};
        lsum[g] += pa; lsum[g] += pbv; lsum[g] += pc; lsum[g] += pd;
        u32x4 pk;
        pk.x = pack_bf16(e0, e1); pk.y = pack_bf16(e2, e3);
        pk.z = pack_bf16(f0, f1); pk.w = pack_bf16(f2, f3);
        pb[g] = __builtin_bit_cast(bfrag, pk);
      }
      bfrag vlo = *(const bfrag*)&Vt[buf][l16 * 68 + kb + quad * 8];
      bfrag vhi = *(const bfrag*)&Vt[buf][(16 + l16) * 68 + kb + quad * 8];
      __builtin_amdgcn_s_setprio(1);
#pragma unroll
      for (int g = 0; g < 2; ++g) {
        olo[g] = __builtin_amdgcn_mfma_f32_16x16x32_bf16(pb[g], vlo, olo[g], 0, 0, 0);
        ohi[g] = __builtin_amdgcn_mfma_f32_16x16x32_bf16(pb[g], vhi, ohi[g], 0, 0, 0);
      }
      __builtin_amdgcn_s_setprio(0);
    }
    buf ^= 1;
  }
  uint16_t* Ob = (uint16_t*)OpB;
  const long obase = ((long)ks * 16 + bh) * 4096;
  const int qgb = qt * 128 + w * 32;
#pragma unroll
  for (int g = 0; g < 2; ++g) {
    float ls = lsum[g].x + lsum[g].y;
    ls += __shfl_xor(ls, 16); ls += __shfl_xor(ls, 32);
    if (quad == 0)
      lpart[obase + qrow0 + g * 16] = ls;
#pragma unroll
    for (int r = 0; r < 4; ++r) {
      int q = qgb + g * 16 + quad * 4 + r;
      uint32_t pk = pack_bf16(olo[g][r], ohi[g][r]);
      Ob[(obase + q) * 32 + l16] = (uint16_t)pk;
      Ob[(obase + q) * 32 + l16 + 16] = (uint16_t)(pk >> 16);
    }
  }
}

// ---------------- proj GEMM, 64x64 tiles (512 blocks = 2/CU) ---------------
// A[row][d] = (sum_ks OpB) / (sum_ks lpart) fused in A-staging.
__global__ __launch_bounds__(256) void proj_kernel(const short* __restrict__ OpB,
                                                   const float* __restrict__ lpart,
                                                   const short* __restrict__ Bt,
                                                   const float* __restrict__ bias,
                                                   float* __restrict__ out) {
  __shared__ short As[64 * 40];
  __shared__ short Bs[64 * 40];
  const int mt = blockIdx.x, nt = blockIdx.y;   // mt 0..127, nt 0..3
  const int tid = threadIdx.x;
  const int w = tid >> 6, lane = tid & 63, l16 = lane & 15, quad = lane >> 4;
  const int ar = tid >> 2, ak = (tid & 3) * 8;   // A: 64 rows x 32 cols/iter
  const int br = tid >> 2, bk = (tid & 3) * 8;
  f32x4 acc[4] = {};

  const int row = mt * 64 + ar;
  const int q = row & 4095, bq = row >> 12;
  const short* Brow = Bt + (long)(nt * 64 + br) * 256 + bk;

  long lb0 = (long)(bq * 8) * 4096 + q;
  bfrag pa[4];               // [ks]: 8 shorts = d ak..ak+7
  f32x4 pl;
#pragma unroll
  for (int ks = 0; ks < 4; ++ks) {
    long base = (lb0 + (long)ks * 16 * 4096) * 32 + ak;
    pa[ks] = *(const bfrag*)&OpB[base];
    pl[ks] = lpart[lb0 + (long)ks * 16 * 4096];
  }
  bfrag b8 = *(const bfrag*)Brow;

  for (int kk = 0; kk < 8; ++kk) {
    float linv = 1.f / (pl[0] + pl[1] + pl[2] + pl[3]);
    short av[8];
#pragma unroll
    for (int jj2 = 0; jj2 < 8; jj2 += 2) {
      float v0 = (bf2f(pa[0][jj2]) + bf2f(pa[1][jj2]) +
                  bf2f(pa[2][jj2]) + bf2f(pa[3][jj2])) * linv;
      float v1 = (bf2f(pa[0][jj2+1]) + bf2f(pa[1][jj2+1]) +
                  bf2f(pa[2][jj2+1]) + bf2f(pa[3][jj2+1])) * linv;
      *(uint32_t*)&av[jj2] = pack_bf16(v0, v1);
    }
    __syncthreads();
    *(bfrag*)&As[ar * 40 + ak] = *(bfrag*)&av[0];
    *(bfrag*)&Bs[br * 40 + bk] = b8;
    __syncthreads();
    int kn = (kk < 7) ? (kk + 1) : 7;
    long lbn = (long)(bq * 8 + kn) * 4096 + q;
#pragma unroll
    for (int ks = 0; ks < 4; ++ks) {
      long base = (lbn + (long)ks * 16 * 4096) * 32 + ak;
      pa[ks] = *(const bfrag*)&OpB[base];
      pl[ks] = lpart[lbn + (long)ks * 16 * 4096];
    }
    b8 = *(const bfrag*)(Brow + kn * 32);

    bfrag a0 = *(const bfrag*)&As[(w * 16 + l16) * 40 + quad * 8];
#pragma unroll
    for (int c = 0; c < 4; ++c) {
      bfrag bf = *(const bfrag*)&Bs[(c * 16 + l16) * 40 + quad * 8];
      acc[c] = __builtin_amdgcn_mfma_f32_16x16x32_bf16(a0, bf, acc[c], 0, 0, 0);
    }
  }
  const int rowb = mt * 64 + w * 16 + quad * 4;
#pragma unroll
  for (int c = 0; c < 4; ++c) {
    int col = nt * 64 + c * 16 + l16;
    float bv = bias[col];
#pragma unroll
    for (int r = 0; r < 4; ++r)
      out[(long)(rowb + r) * 256 + col] = acc[c][r] + bv;
  }
}

extern "C" void kernel_launch(void* const* d_in, const int* in_sizes, int n_in,
                              void* d_out, int out_size, void* d_ws, size_t ws_size,
                              hipStream_t stream) {
  const float* x      = (const float*)d_in[0];
  // d_in[1] = cond (unused by reference)
  const int*   t      = (const int*)d_in[2];
  const float* emb    = (const float*)d_in[3];
  const float* ada_w  = (const float*)d_in[4];
  const float* ada_b  = (const float*)d_in[5];
  const float* qkv_w  = (const float*)d_in[6];
  const float* qkv_b  = (const float*)d_in[7];
  const float* proj_w = (const float*)d_in[8];
  const float* proj_b = (const float*)d_in[9];

  char* ws = (char*)d_ws;
  float* scsh     = (float*)(ws);                  //   4 KB  [2][512]
  short* qkv_wt   = (short*)(ws + 4096);           // 384 KB  [768][256]
  short* proj_wt  = (short*)(ws + 397312);         // 128 KB  [256][256]
  float* xn       = (float*)(ws + 528384);         //   8 MB  [8192][256] fp32
  short* qk_out   = (short*)(ws + 8916992);        //   8 MB  [8192][512]
  short* vT       = (short*)(ws + 17305600);       //   4 MB  [16][32][4096]
  short* OpB      = (short*)(ws + 21499904);       //  16 MB  [4][16][4096][32] bf16
  float* lpart    = (float*)(ws + 38277120);       //   1 MB  [4][16][4096]

  const float QS = 0.17677669529663687f * 1.4426950408889634f;  // scale*log2e

  prep_kernel<<<2128, 256, 0, stream>>>(emb, t, ada_w, ada_b, scsh,
                                        qkv_w, qkv_wt, proj_w, proj_wt, x, xn);
  gemm_qkv<<<768, 256, 0, stream>>>(xn, scsh, qkv_wt, qkv_b, QS, qk_out, vT);
  attn_kernel<<<2048, 256, 0, stream>>>(qk_out, vT, OpB, lpart);
  proj_kernel<<<dim3(128, 4), 256, 0, stream>>>(OpB, lpart, proj_wt, proj_b,
                                                (float*)d_out);
}

// Round 9
// 164.172 us; speedup vs baseline: 1.3917x; 1.0387x over previous
//
#include <hip/hip_runtime.h>
#include <hip/hip_bf16.h>
#include <stdint.h>

typedef __attribute__((ext_vector_type(8))) short bfrag;
typedef __attribute__((ext_vector_type(4))) short bfrag4;
typedef __attribute__((ext_vector_type(4))) float f32x4;
typedef __attribute__((ext_vector_type(2))) float f32x2;
typedef __attribute__((ext_vector_type(2))) unsigned int u32x2;
typedef __attribute__((ext_vector_type(4))) unsigned int u32x4;

__device__ inline short f2bf(float f) {
  union { float f; uint32_t u; } v; v.f = f;
  uint32_t u = v.u;
  uint32_t r = (u + 0x7fffu + ((u >> 16) & 1u)) >> 16;
  return (short)r;
}
__device__ inline float bf2f(short s) {
  return __builtin_bit_cast(float, (uint32_t)((uint32_t)(uint16_t)s << 16));
}

#if __has_builtin(__builtin_amdgcn_cvt_pk_bf16_f32)
typedef __attribute__((ext_vector_type(2))) __bf16 bf16x2_t;
__device__ inline uint32_t pack_bf16(float a, float b) {
  bf16x2_t r = __builtin_amdgcn_cvt_pk_bf16_f32(a, b);
  return __builtin_bit_cast(uint32_t, r);
}
#else
__device__ inline uint32_t pack_bf16(float a, float b) {
  uint32_t ua = __builtin_bit_cast(uint32_t, a) + 0x8000u;
  uint32_t ub = __builtin_bit_cast(uint32_t, b) + 0x8000u;
  return __builtin_amdgcn_perm(ub, ua, 0x07060302);
}
#endif

// Drain-free workgroup barrier: only my own LDS ops must be complete.
__device__ inline void lds_barrier() {
  asm volatile("s_waitcnt lgkmcnt(0)" ::: "memory");
  __builtin_amdgcn_s_barrier();
  asm volatile("" ::: "memory");
}

// ---------------- prep: ada (blocks 0-15) + weight transposes (16-79) ------
__global__ __launch_bounds__(256) void prep_kernel(
    const float* __restrict__ emb_table, const int* __restrict__ t,
    const float* __restrict__ ada_w, const float* __restrict__ ada_b,
    float* __restrict__ scsh,
    const float* __restrict__ qkv_w, short* __restrict__ qkv_wt,
    const float* __restrict__ proj_w, short* __restrict__ proj_wt) {
  __shared__ float smem[64 * 65];
  const int blk = blockIdx.x;
  const int tid = threadIdx.x;
  if (blk < 16) {
    float* se = smem;
    float* part = smem + 256;
    int b = blk >> 3, ox = blk & 7;
    int tt = t[b];
    float e = emb_table[tt * 256 + tid];
    se[tid] = e / (1.f + __expf(-e));
    __syncthreads();
    int ol = tid & 63, kc = tid >> 6;
    int o = ox * 64 + ol;
    float acc = 0.f;
#pragma unroll 8
    for (int k = kc * 64; k < (kc + 1) * 64; ++k) acc += se[k] * ada_w[k * 512 + o];
    part[tid] = acc;
    __syncthreads();
    if (tid < 64) {
      int oo = ox * 64 + tid;
      scsh[b * 512 + oo] =
          part[tid] + part[64 + tid] + part[128 + tid] + part[192 + tid] + ada_b[oo];
    }
  } else {
    const float* W; short* Wt; int N, lb;
    if (blk < 64) { W = qkv_w; Wt = qkv_wt; N = 768; lb = blk - 16; }
    else          { W = proj_w; Wt = proj_wt; N = 256; lb = blk - 64; }
    float (*tile)[65] = (float(*)[65])smem;
    int k0 = (lb & 3) * 64, n0 = (lb >> 2) * 64;
    int r = tid >> 2, c0 = (tid & 3) * 16;
    const float* src = W + (long)(k0 + r) * N + n0 + c0;
#pragma unroll
    for (int j = 0; j < 16; j += 4) {
      float4 v = *(const float4*)(src + j);
      tile[r][c0 + j] = v.x; tile[r][c0 + j + 1] = v.y;
      tile[r][c0 + j + 2] = v.z; tile[r][c0 + j + 3] = v.w;
    }
    __syncthreads();
    int nl = tid >> 2, kc = (tid & 3) * 16;
    short outv[16];
#pragma unroll
    for (int j = 0; j < 16; ++j) outv[j] = f2bf(tile[kc + j][nl]);
    short* dst = Wt + (long)(n0 + nl) * 256 + k0 + kc;
    *(bfrag*)dst = *(bfrag*)&outv[0];
    *(bfrag*)(dst + 8) = *(bfrag*)&outv[8];
  }
}

// ---------------- LayerNorm + (1+sc)*xn + sh -> bf16, wave-per-row ---------
__global__ __launch_bounds__(256) void ln_kernel(const float* __restrict__ x,
                                                 const float* __restrict__ scsh,
                                                 short* __restrict__ xb) {
  int row = blockIdx.x * 4 + (threadIdx.x >> 6);   // 2048 blocks x 4 rows
  int b = row >> 12;
  int lane = threadIdx.x & 63;
  float4 v = *(const float4*)(x + (long)row * 256 + lane * 4);
  float s = v.x + v.y + v.z + v.w;
  float sq = v.x * v.x + v.y * v.y + v.z * v.z + v.w * v.w;
#pragma unroll
  for (int off = 32; off > 0; off >>= 1) {
    s += __shfl_xor(s, off);
    sq += __shfl_xor(sq, off);
  }
  float mu = s * (1.f / 256.f);
  float var = sq * (1.f / 256.f) - mu * mu;
  float rstd = rsqrtf(var + 1e-5f);
  const float* scp = scsh + b * 512 + lane * 4;
  float4 sc = *(const float4*)scp;
  float4 sh = *(const float4*)(scp + 256);
  float y0 = (v.x - mu) * rstd * (1.f + sc.x) + sh.x;
  float y1 = (v.y - mu) * rstd * (1.f + sc.y) + sh.y;
  float y2 = (v.z - mu) * rstd * (1.f + sc.z) + sh.z;
  float y3 = (v.w - mu) * rstd * (1.f + sc.w) + sh.w;
  u32x2 o; o.x = pack_bf16(y0, y1); o.y = pack_bf16(y2, y3);
  *(u32x2*)&xb[(long)row * 256 + lane * 4] = o;
}

// ---------------- QKV GEMM, 128x64 tile: qkv = xb * qkv_wt^T + bias --------
// cols 0..511 -> qk bf16 (cols<256 scaled by qscale); 512..767 -> vT (transposed).
__global__ __launch_bounds__(256) void gemm_qkv(const short* __restrict__ A,
                                                const short* __restrict__ Bt,
                                                const float* __restrict__ bias,
                                                float qscale,
                                                short* __restrict__ qk,
                                                short* __restrict__ vT) {
  __shared__ short As[128 * 40];
  __shared__ short Bs[64 * 40];
  const int mt = blockIdx.x, nt = blockIdx.y;
  const int tid = threadIdx.x;
  const int w = tid >> 6, lane = tid & 63, l16 = lane & 15, quad = lane >> 4;
  const int ar = tid >> 1, ak = (tid & 1) * 16;
  const int br = tid >> 2, bk = (tid & 3) * 8;
  f32x4 acc[2][4] = {};
  const short* Arow = A + (long)(mt * 128 + ar) * 256 + ak;
  const short* Brow = Bt + (long)(nt * 64 + br) * 256 + bk;
  bfrag a8a = *(const bfrag*)Arow;
  bfrag a8b = *(const bfrag*)(Arow + 8);
  bfrag b8  = *(const bfrag*)Brow;
  for (int kk = 0; kk < 8; ++kk) {
    __syncthreads();
    *(bfrag*)&As[ar * 40 + ak] = a8a;
    *(bfrag*)&As[ar * 40 + ak + 8] = a8b;
    *(bfrag*)&Bs[br * 40 + bk] = b8;
    __syncthreads();
    int kn = (kk < 7) ? (kk + 1) : 7;
    a8a = *(const bfrag*)(Arow + kn * 32);
    a8b = *(const bfrag*)(Arow + kn * 32 + 8);
    b8  = *(const bfrag*)(Brow + kn * 32);
    bfrag a0 = *(const bfrag*)&As[(w * 32 + l16) * 40 + quad * 8];
    bfrag a1 = *(const bfrag*)&As[(w * 32 + 16 + l16) * 40 + quad * 8];
#pragma unroll
    for (int c = 0; c < 4; ++c) {
      bfrag bf = *(const bfrag*)&Bs[(c * 16 + l16) * 40 + quad * 8];
      acc[0][c] = __builtin_amdgcn_mfma_f32_16x16x32_bf16(a0, bf, acc[0][c], 0, 0, 0);
      acc[1][c] = __builtin_amdgcn_mfma_f32_16x16x32_bf16(a1, bf, acc[1][c], 0, 0, 0);
    }
  }
  const int rowb = mt * 128 + w * 32 + quad * 4;
  if (nt < 8) {  // Q,K columns -> qk pitch 512
#pragma unroll
    for (int rg = 0; rg < 2; ++rg) {
      int row0 = rowb + rg * 16;
#pragma unroll
      for (int c = 0; c < 4; ++c) {
        int col = nt * 64 + c * 16 + l16;
        float bv = bias[col];
        float mult = (col < 256) ? qscale : 1.0f;
#pragma unroll
        for (int r = 0; r < 4; ++r)
          qk[(long)(row0 + r) * 512 + col] = f2bf((acc[rg][c][r] + bv) * mult);
      }
    }
  } else {  // V columns -> vT[bh][d][key]
    const int bb = mt >> 5;
#pragma unroll
    for (int rg = 0; rg < 2; ++rg) {
      int keyl = (rowb + rg * 16) & 4095;
#pragma unroll
      for (int c = 0; c < 4; ++c) {
        int col = nt * 64 + c * 16 + l16;
        float bv = bias[col];
        int d = col - 512;
        u32x2 dd;
        dd.x = pack_bf16(acc[rg][c][0] + bv, acc[rg][c][1] + bv);
        dd.y = pack_bf16(acc[rg][c][2] + bv, acc[rg][c][3] + bv);
        *(u32x2*)&vT[((long)(bb * 8 + (d >> 5)) * 32 + (d & 31)) * 4096 + keyl] = dd;
      }
    }
  }
}

// ---------------- flash attention (S^T, O^T PV, KVBLK=128) -----------------
// Grid: 2048 blocks, XCD-aware mapping, 128 q rows/block, keys [ks*1024,+1024).
// 128-key staged tiles: one barrier per 128 keys (8 total, half of R5) and a
// ~2x longer compute phase for every global prefetch to land under.
// LDS 35.3 KB -> 4 blocks/CU (occupancy proven non-binding in R1).
__global__ __launch_bounds__(256) void attn_kernel(const short* __restrict__ qk,
                                                   const short* __restrict__ vT,
                                                   short* __restrict__ OpB,
                                                   float* __restrict__ lpart) {
  const int bid = blockIdx.x;
  const int c = bid & 7, j = bid >> 3;          // bijective: 2048 = 8 * 256
  const int bh = c * 2 + (j >> 7);
  const int qt = j & 31;
  const int ks = (j >> 5) & 3;
  const int b = bh >> 3, hh = bh & 7;
  const int tid = threadIdx.x;
  const int w = tid >> 6, lane = tid & 63, l16 = lane & 15, quad = lane >> 4;
  const int sig0 = ((l16 >> 2) * 8) + (l16 & 3);   // key-slot permutation

  __shared__ short Ks[2][128 * 36];
  __shared__ short Vt[2][32 * 132];

  const long rowbase = (long)b * 4096;
  const int qrow0 = qt * 128 + w * 32 + l16;
  bfrag qf[2];
#pragma unroll
  for (int g = 0; g < 2; ++g)
    qf[g] = *(const bfrag*)&qk[(rowbase + qrow0 + g * 16) * 512 + hh * 32 + quad * 8];

  f32x4 olo[2] = {}, ohi[2] = {};
  f32x2 lsum[2] = {};

  const int si = tid >> 2, sk = (tid & 3) * 8;
  const int vrow = tid >> 3, vcol = (tid & 7) * 8;
  const short* ksrc = qk + rowbase * 512 + 256 + hh * 32 + (long)si * 512 + sk;
  const short* vsrc = vT + ((long)bh * 32 + vrow) * 4096 + vcol;

  const int kbase = ks * 1024;
  // prefetch iter 0 (keys kbase..kbase+127): two 64-key halves
  bfrag k8a = *(const bfrag*)(ksrc + (long)kbase * 512);
  bfrag k8b = *(const bfrag*)(ksrc + (long)(kbase + 64) * 512);
  bfrag v8a = *(const bfrag*)(vsrc + kbase);
  bfrag v8b = *(const bfrag*)(vsrc + kbase + 64);

  int buf = 0;
  for (int i = 0; i < 8; ++i) {
    *(bfrag*)&Ks[buf][si * 36 + sk] = k8a;
    *(bfrag*)&Ks[buf][(si + 64) * 36 + sk] = k8b;
    *(bfrag*)&Vt[buf][vrow * 132 + vcol] = v8a;
    *(bfrag*)&Vt[buf][vrow * 132 + 64 + vcol] = v8b;
    lds_barrier();                 // drain-free: prefetch stays in flight
    int nn = (i < 7) ? (i + 1) : 7;
    int kb_n = kbase + nn * 128;
    k8a = *(const bfrag*)(ksrc + (long)kb_n * 512);
    k8b = *(const bfrag*)(ksrc + (long)(kb_n + 64) * 512);
    v8a = *(const bfrag*)(vsrc + kb_n);
    v8b = *(const bfrag*)(vsrc + kb_n + 64);

#pragma unroll
    for (int p = 0; p < 4; ++p) {              // four 32-key pair-tiles
      const int kb = p * 32;
      bfrag kf0 = *(const bfrag*)&Ks[buf][(kb + sig0) * 36 + quad * 8];
      bfrag kf1 = *(const bfrag*)&Ks[buf][(kb + sig0 + 4) * 36 + quad * 8];
      f32x4 z = {0, 0, 0, 0};
      f32x4 s0[2], s1[2];
      __builtin_amdgcn_s_setprio(1);
      s0[0] = __builtin_amdgcn_mfma_f32_16x16x32_bf16(kf0, qf[0], z, 0, 0, 0);
      s0[1] = __builtin_amdgcn_mfma_f32_16x16x32_bf16(kf0, qf[1], z, 0, 0, 0);
      s1[0] = __builtin_amdgcn_mfma_f32_16x16x32_bf16(kf1, qf[0], z, 0, 0, 0);
      s1[1] = __builtin_amdgcn_mfma_f32_16x16x32_bf16(kf1, qf[1], z, 0, 0, 0);
      __builtin_amdgcn_s_setprio(0);
      bfrag pb[2];
#pragma unroll
      for (int g = 0; g < 2; ++g) {
        float e0 = __builtin_amdgcn_exp2f(s0[g][0]);
        float e1 = __builtin_amdgcn_exp2f(s0[g][1]);
        float e2 = __builtin_amdgcn_exp2f(s0[g][2]);
        float e3 = __builtin_amdgcn_exp2f(s0[g][3]);
        float f0 = __builtin_amdgcn_exp2f(s1[g][0]);
        float f1 = __builtin_amdgcn_exp2f(s1[g][1]);
        float f2 = __builtin_amdgcn_exp2f(s1[g][2]);
        float f3 = __builtin_amdgcn_exp2f(s1[g][3]);
        f32x2 pa = {e0, e1}, pbv = {e2, e3}, pc = {f0, f1}, pd = {f2, f3};
        lsum[g] += pa; lsum[g] += pbv; lsum[g] += pc; lsum[g] += pd;
        u32x4 pk;
        pk.x = pack_bf16(e0, e1); pk.y = pack_bf16(e2, e3);
        pk.z = pack_bf16(f0, f1); pk.w = pack_bf16(f2, f3);
        pb[g] = __builtin_bit_cast(bfrag, pk);
      }
      bfrag vlo = *(const bfrag*)&Vt[buf][l16 * 132 + kb + quad * 8];
      bfrag vhi = *(const bfrag*)&Vt[buf][(16 + l16) * 132 + kb + quad * 8];
      __builtin_amdgcn_s_setprio(1);
#pragma unroll
      for (int g = 0; g < 2; ++g) {
        olo[g] = __builtin_amdgcn_mfma_f32_16x16x32_bf16(pb[g], vlo, olo[g], 0, 0, 0);
        ohi[g] = __builtin_amdgcn_mfma_f32_16x16x32_bf16(pb[g], vhi, ohi[g], 0, 0, 0);
      }
      __builtin_amdgcn_s_setprio(0);
    }
    buf ^= 1;
  }
  // epilogue: O^T layout -> OpB[q][d] u16 stores (once per block)
  uint16_t* Ob = (uint16_t*)OpB;
  const long obase = ((long)ks * 16 + bh) * 4096;
  const int qgb = qt * 128 + w * 32;
#pragma unroll
  for (int g = 0; g < 2; ++g) {
    float ls = lsum[g].x + lsum[g].y;
    ls += __shfl_xor(ls, 16); ls += __shfl_xor(ls, 32);
    if (quad == 0)
      lpart[obase + qrow0 + g * 16] = ls;
#pragma unroll
    for (int r = 0; r < 4; ++r) {
      int q = qgb + g * 16 + quad * 4 + r;
      uint32_t pk = pack_bf16(olo[g][r], ohi[g][r]);
      Ob[(obase + q) * 32 + l16] = (uint16_t)pk;
      Ob[(obase + q) * 32 + l16 + 16] = (uint16_t)(pk >> 16);
    }
  }
}

// ---------------- proj GEMM with fused key-split reduce --------------------
// A[row][d] = (sum_ks OpB) / (sum_ks lpart), computed during A-staging.
// Head hh == kk (K-step index): A cols kk*32..+31 come from OpB head kk.
// C = A[8192,256] * proj_wt^T + proj_b -> fp32 out. Grid (64,4), 128x64 tile.
__global__ __launch_bounds__(256) void proj_kernel(const short* __restrict__ OpB,
                                                   const float* __restrict__ lpart,
                                                   const short* __restrict__ Bt,
                                                   const float* __restrict__ bias,
                                                   float* __restrict__ out) {
  __shared__ short As[128 * 40];
  __shared__ short Bs[64 * 40];
  const int mt = blockIdx.x, nt = blockIdx.y;
  const int tid = threadIdx.x;
  const int w = tid >> 6, lane = tid & 63, l16 = lane & 15, quad = lane >> 4;
  const int ar = tid >> 1, ak = (tid & 1) * 16;   // A: 128 rows x 32 cols/iter
  const int br = tid >> 2, bk = (tid & 3) * 8;
  f32x4 acc[2][4] = {};

  const int row = mt * 128 + ar;
  const int q = row & 4095, bq = row >> 12;
  const short* Brow = Bt + (long)(nt * 64 + br) * 256 + bk;

  // prefetch kk=0 (head hh = kk; OpB row index = (ks*16 + bq*8 + kk)*4096 + q)
  long lb0 = (long)(bq * 8) * 4096 + q;
  bfrag pa[4][2];            // [ks][half]: 16 shorts per ks = d ak..ak+15
  f32x4 pl;
#pragma unroll
  for (int ks = 0; ks < 4; ++ks) {
    long base = (lb0 + (long)ks * 16 * 4096) * 32 + ak;
    pa[ks][0] = *(const bfrag*)&OpB[base];
    pa[ks][1] = *(const bfrag*)&OpB[base + 8];
    pl[ks] = lpart[lb0 + (long)ks * 16 * 4096];
  }
  bfrag b8 = *(const bfrag*)Brow;

  for (int kk = 0; kk < 8; ++kk) {
    // combine partials -> bf16 A fragment
    float linv = 1.f / (pl[0] + pl[1] + pl[2] + pl[3]);
    short av[16];
#pragma unroll
    for (int h = 0; h < 2; ++h) {
#pragma unroll
      for (int j = 0; j < 8; j += 2) {
        float v0 = (bf2f(pa[0][h][j]) + bf2f(pa[1][h][j]) +
                    bf2f(pa[2][h][j]) + bf2f(pa[3][h][j])) * linv;
        float v1 = (bf2f(pa[0][h][j+1]) + bf2f(pa[1][h][j+1]) +
                    bf2f(pa[2][h][j+1]) + bf2f(pa[3][h][j+1])) * linv;
        *(uint32_t*)&av[h * 8 + j] = pack_bf16(v0, v1);
      }
    }
    __syncthreads();
    *(bfrag*)&As[ar * 40 + ak] = *(bfrag*)&av[0];
    *(bfrag*)&As[ar * 40 + ak + 8] = *(bfrag*)&av[8];
    *(bfrag*)&Bs[br * 40 + bk] = b8;
    __syncthreads();
    // prefetch next kk
    int kn = (kk < 7) ? (kk + 1) : 7;
    long lbn = (long)(bq * 8 + kn) * 4096 + q;
#pragma unroll
    for (int ks = 0; ks < 4; ++ks) {
      long base = (lbn + (long)ks * 16 * 4096) * 32 + ak;
      pa[ks][0] = *(const bfrag*)&OpB[base];
      pa[ks][1] = *(const bfrag*)&OpB[base + 8];
      pl[ks] = lpart[lbn + (long)ks * 16 * 4096];
    }
    b8 = *(const bfrag*)(Brow + kn * 32);

    bfrag a0 = *(const bfrag*)&As[(w * 32 + l16) * 40 + quad * 8];
    bfrag a1 = *(const bfrag*)&As[(w * 32 + 16 + l16) * 40 + quad * 8];
#pragma unroll
    for (int c = 0; c < 4; ++c) {
      bfrag bf = *(const bfrag*)&Bs[(c * 16 + l16) * 40 + quad * 8];
      acc[0][c] = __builtin_amdgcn_mfma_f32_16x16x32_bf16(a0, bf, acc[0][c], 0, 0, 0);
      acc[1][c] = __builtin_amdgcn_mfma_f32_16x16x32_bf16(a1, bf, acc[1][c], 0, 0, 0);
    }
  }
  const int rowb = mt * 128 + w * 32 + quad * 4;
#pragma unroll
  for (int rg = 0; rg < 2; ++rg) {
    int row0 = rowb + rg * 16;
#pragma unroll
    for (int c = 0; c < 4; ++c) {
      int col = nt * 64 + c * 16 + l16;
      float bv = bias[col];
#pragma unroll
      for (int r = 0; r < 4; ++r)
        out[(long)(row0 + r) * 256 + col] = acc[rg][c][r] + bv;
    }
  }
}

extern "C" void kernel_launch(void* const* d_in, const int* in_sizes, int n_in,
                              void* d_out, int out_size, void* d_ws, size_t ws_size,
                              hipStream_t stream) {
  const float* x      = (const float*)d_in[0];
  // d_in[1] = cond (unused by reference)
  const int*   t      = (const int*)d_in[2];
  const float* emb    = (const float*)d_in[3];
  const float* ada_w  = (const float*)d_in[4];
  const float* ada_b  = (const float*)d_in[5];
  const float* qkv_w  = (const float*)d_in[6];
  const float* qkv_b  = (const float*)d_in[7];
  const float* proj_w = (const float*)d_in[8];
  const float* proj_b = (const float*)d_in[9];

  char* ws = (char*)d_ws;
  float* scsh     = (float*)(ws);                  //   4 KB  [2][512]
  short* qkv_wt   = (short*)(ws + 4096);           // 384 KB  [768][256]
  short* proj_wt  = (short*)(ws + 397312);         // 128 KB  [256][256]
  short* xb       = (short*)(ws + 528384);         //   4 MB  [8192][256]
  short* qk_out   = (short*)(ws + 4722688);        //   8 MB  [8192][512]
  short* vT       = (short*)(ws + 13111296);       //   4 MB  [16][32][4096]
  short* OpB      = (short*)(ws + 21499904);       //  16 MB  [4][16][4096][32] bf16
  float* lpart    = (float*)(ws + 38277120);       //   1 MB  [4][16][4096]

  const float QS = 0.17677669529663687f * 1.4426950408889634f;  // scale*log2e

  prep_kernel<<<80, 256, 0, stream>>>(emb, t, ada_w, ada_b, scsh,
                                      qkv_w, qkv_wt, proj_w, proj_wt);
  ln_kernel<<<2048, 256, 0, stream>>>(x, scsh, xb);
  gemm_qkv<<<dim3(64, 12), 256, 0, stream>>>(xb, qkv_wt, qkv_b, QS, qk_out, vT);
  attn_kernel<<<2048, 256, 0, stream>>>(qk_out, vT, OpB, lpart);
  proj_kernel<<<dim3(64, 4), 256, 0, stream>>>(OpB, lpart, proj_wt, proj_b,
                                               (float*)d_out);
}